// Round 7
// baseline (106.869 us; speedup 1.0000x reference)
//
#include <hip/hip_runtime.h>

// Linear interpolation: 8.4M samples vs 16384 sorted knots.
// R7: R5-proven LDS structure (sx f32 / sys u32 / sT u16, NB=14336, aligned
// 8-candidate window) + direct (xi,ys) selection from a sys window (no
// dependent gather, no index math) + software-pipelined streaming loads.
// All LDS vector access strictly through the array's own element type.

#define NB 14336          // u16 table = 28 KB LDS
#define NKMAX 16384
#define PAD 16

typedef float    f32x4 __attribute__((ext_vector_type(4)));
typedef unsigned u32x4 __attribute__((ext_vector_type(4)));

__device__ __forceinline__ int bucket_of(float v, float lo, float inv_w) {
    // MUST be the identical expression in both kernels (monotone in fp32).
    return (int)((v - lo) * inv_w);
}

__device__ __forceinline__ unsigned pack_ys(float y, float s) {
    _Float16 hy = (_Float16)y, hs = (_Float16)s;
    unsigned short uy = __builtin_bit_cast(unsigned short, hy);
    unsigned short us = __builtin_bit_cast(unsigned short, hs);
    return (unsigned)uy | ((unsigned)us << 16);
}

__device__ __forceinline__ float lerp_ys(float dx, unsigned u) {
    float hy = (float)__builtin_bit_cast(_Float16, (unsigned short)(u & 0xffffu));
    float hs = (float)__builtin_bit_cast(_Float16, (unsigned short)(u >> 16));
    return fmaf(dx, hs, hy);
}

// ---------------- Kernel A: packed (y,slope) + u16 bucket->lo table ----------------
__global__ void build_tbl(const float* __restrict__ xp, const float* __restrict__ yp,
                          unsigned* __restrict__ ysg, unsigned short* __restrict__ tbl,
                          int nk) {
    int i = blockIdx.x * blockDim.x + threadIdx.x;
    float lo = xp[0];
    float inv_w = (float)NB / (xp[nk - 1] - lo);
    if (i < nk) {
        float y0 = yp[i];
        float slope = 0.0f;
        if (i < nk - 1) slope = (yp[i + 1] - y0) / (xp[i + 1] - xp[i]);
        ysg[i] = pack_ys(y0, slope);
    }
    if (i < NB) {
        // lo(i) = largest j with bucket(xp[j]) <= i-1   (monotone predicate)
        int v = 0;
        if (i > 0) {
            int loj = -1, hij = nk - 1;
            while (loj < hij) {
                int mid = (loj + hij + 1) >> 1;
                if (bucket_of(xp[mid], lo, inv_w) <= i - 1) loj = mid; else hij = mid - 1;
            }
            v = loj < 0 ? 0 : (loj > nk - 2 ? nk - 2 : loj);
        }
        tbl[i] = (unsigned short)v;
    }
}

// ---------------- Kernel B: interpolate ----------------
__global__ __launch_bounds__(1024) void interp(
        const f32x4* __restrict__ xs4, const float* __restrict__ xp,
        const unsigned* __restrict__ ysg, const unsigned short* __restrict__ tbl,
        f32x4* __restrict__ out4, int n4, int nk) {
    __shared__ __align__(16) float sx[NKMAX + PAD];       // 64.06 KB
    __shared__ __align__(16) unsigned sys[NKMAX + PAD];   // 64.06 KB
    __shared__ unsigned short sT[NB];                     // 28 KB

    {   // fills: vector access only through matching element types (R5-proven)
        const f32x4* xp4 = (const f32x4*)xp;
        f32x4* sx4w = (f32x4*)sx;
        for (int i = threadIdx.x; i < nk / 4; i += 1024) sx4w[i] = xp4[i];
        const u32x4* ysg4 = (const u32x4*)ysg;
        u32x4* sys4w = (u32x4*)sys;
        for (int i = threadIdx.x; i < nk / 4; i += 1024) sys4w[i] = ysg4[i];
        for (int i = threadIdx.x; i < NB; i += 1024) sT[i] = tbl[i];
        if (threadIdx.x < PAD) {
            sx[nk + threadIdx.x] = __builtin_inff();   // never selected
            sys[nk + threadIdx.x] = 0u;
        }
    }

    float lo = xp[0];
    float inv_w = (float)NB / (xp[nk - 1] - lo);
    __syncthreads();

    const f32x4* sx4 = (const f32x4*)sx;
    const u32x4* sys4 = (const u32x4*)sys;

    int tid = blockIdx.x * blockDim.x + threadIdx.x;
    int T = gridDim.x * blockDim.x;

    int t = tid;
    f32x4 xa, xb;
    bool has1 = (t < n4), has2 = (t + T < n4);
    if (has1) xa = __builtin_nontemporal_load(&xs4[t]);
    if (has2) xb = __builtin_nontemporal_load(&xs4[t + T]);

    while (has1) {
        int tn = t + 2 * T;
        f32x4 xan, xbn;
        bool h1n = (tn < n4), h2n = (tn + T < n4);
        if (h1n) xan = __builtin_nontemporal_load(&xs4[tn]);          // prefetch
        if (h2n) xbn = __builtin_nontemporal_load(&xs4[tn + T]);

        f32x4 res[2];
        #pragma unroll
        for (int half = 0; half < 2; half++) {
            f32x4 xq = (half == 0) ? xa : xb;
            float x[4] = {xq.x, xq.y, xq.z, xq.w};
            int al[4];
            f32x4 wx0[4], wx1[4];
            u32x4 wy0[4], wy1[4];
            #pragma unroll
            for (int k = 0; k < 4; k++) {
                int b = bucket_of(x[k], lo, inv_w);
                b = min(max(b, 0), NB - 1);
                al[k] = ((int)sT[b]) & ~3;
                int q = al[k] >> 2;
                wx0[k] = sx4[q];       // 4 independent window chains -> MLP
                wx1[k] = sx4[q + 1];
                wy0[k] = sys4[q];
                wy1[k] = sys4[q + 1];
            }
            #pragma unroll
            for (int k = 0; k < 4; k++) {
                float xk = x[k];
                float xi = wx0[k].x; unsigned ys = wy0[k].x;   // sx[al] <= xk guaranteed
                if (wx0[k].y <= xk) { xi = wx0[k].y; ys = wy0[k].y; }
                if (wx0[k].z <= xk) { xi = wx0[k].z; ys = wy0[k].z; }
                if (wx0[k].w <= xk) { xi = wx0[k].w; ys = wy0[k].w; }
                if (wx1[k].x <= xk) { xi = wx1[k].x; ys = wy1[k].x; }
                if (wx1[k].y <= xk) { xi = wx1[k].y; ys = wy1[k].y; }
                if (wx1[k].z <= xk) { xi = wx1[k].z; ys = wy1[k].z; }
                bool tail = (wx1[k].w <= xk);
                if (tail) { xi = wx1[k].w; ys = wy1[k].w; }
                if (tail) {
                    // window exhausted (rare): linear walk, exec-masked off
                    int j = al[k] + 7;
                    while (sx[j + 1] <= xk) j++;
                    xi = sx[j]; ys = sys[j];
                }
                res[half][k] = lerp_ys(xk - xi, ys);
            }
        }
        __builtin_nontemporal_store(res[0], &out4[t]);
        if (has2) __builtin_nontemporal_store(res[1], &out4[t + T]);

        t = tn; xa = xan; xb = xbn; has1 = h1n; has2 = h2n;
    }
}

extern "C" void kernel_launch(void* const* d_in, const int* in_sizes, int n_in,
                              void* d_out, int out_size, void* d_ws, size_t ws_size,
                              hipStream_t stream) {
    const float* xs = (const float*)d_in[0];
    const float* xp = (const float*)d_in[1];
    const float* yp = (const float*)d_in[2];
    int ns = in_sizes[0];
    int nk = in_sizes[1];

    // Workspace: ysg (nk u32) | tbl (NB u16)
    unsigned* ysg = (unsigned*)d_ws;
    unsigned short* tbl = (unsigned short*)((char*)d_ws + (size_t)nk * sizeof(unsigned));

    int na = (nk > NB ? nk : NB);
    build_tbl<<<(na + 255) / 256, 256, 0, stream>>>(xp, yp, ysg, tbl, nk);

    int n4 = ns / 4;
    interp<<<256, 1024, 0, stream>>>((const f32x4*)xs, xp, ysg, tbl,
                                     (f32x4*)d_out, n4, nk);
}

// Round 8
// 105.460 us; speedup vs baseline: 1.0134x; 1.0134x over previous
//
#include <hip/hip_runtime.h>

// Linear interpolation: 8.4M samples vs 16384 sorted knots.
// R8: LDS-resident interleaved 8B records {f32 x, bitcast f32 (f16 y, f16 s)}
// in ONE float-typed array (TBAA-safe) + u16 bucket->lo table (NB=16256,
// lambda=1.008). Per sample: 1 ds_read_u16 + 4 adjacent f32x2 reads
// (-> 2x ds_read2_b64, 8B-aligned, no alignment mask). 34 B/sample LDS
// traffic vs R7's 66. Tail (j-lo>2, P~2%) handled by exec-masked walk.

#define NB 16256            // u16 table = 32512 B LDS
#define NKMAX 16384
#define PADR 4              // +INF pad records
#define NREC (NKMAX + PADR)

typedef float f32x4 __attribute__((ext_vector_type(4)));
typedef float f32x2 __attribute__((ext_vector_type(2)));

__device__ __forceinline__ int bucket_of(float v, float lo, float inv_w) {
    // MUST be the identical expression in both kernels (monotone in fp32).
    return (int)((v - lo) * inv_w);
}

__device__ __forceinline__ float pack_ys_f(float y, float s) {
    _Float16 hy = (_Float16)y, hs = (_Float16)s;
    unsigned short uy = __builtin_bit_cast(unsigned short, hy);
    unsigned short us = __builtin_bit_cast(unsigned short, hs);
    unsigned u = (unsigned)uy | ((unsigned)us << 16);
    return __builtin_bit_cast(float, u);
}

__device__ __forceinline__ float lerp_ys(float dx, float ysf) {
    unsigned u = __builtin_bit_cast(unsigned, ysf);
    float hy = (float)__builtin_bit_cast(_Float16, (unsigned short)(u & 0xffffu));
    float hs = (float)__builtin_bit_cast(_Float16, (unsigned short)(u >> 16));
    return fmaf(dx, hs, hy);
}

// ---------------- Kernel A: interleaved records + bucket->lo table ----------------
__global__ void build_tbl(const float* __restrict__ xp, const float* __restrict__ yp,
                          float* __restrict__ recg, unsigned short* __restrict__ tbl,
                          int nk) {
    int i = blockIdx.x * blockDim.x + threadIdx.x;
    float lo = xp[0];
    float inv_w = (float)NB / (xp[nk - 1] - lo);
    if (i < nk + PADR) {
        float x, y, s;
        if (i < nk) {
            x = xp[i]; y = yp[i];
            s = (i < nk - 1) ? (yp[i + 1] - y) / (xp[i + 1] - x) : 0.0f;
        } else {                      // pad: +INF knot, never selected
            x = __builtin_inff(); y = 0.0f; s = 0.0f;
        }
        recg[2 * i]     = x;
        recg[2 * i + 1] = pack_ys_f(y, s);
    }
    if (i < NB) {
        // lo(i) = largest j with bucket(xp[j]) <= i-1   (monotone predicate)
        int v = 0;
        if (i > 0) {
            int loj = -1, hij = nk - 1;
            while (loj < hij) {
                int mid = (loj + hij + 1) >> 1;
                if (bucket_of(xp[mid], lo, inv_w) <= i - 1) loj = mid; else hij = mid - 1;
            }
            v = loj < 0 ? 0 : (loj > nk - 2 ? nk - 2 : loj);
        }
        tbl[i] = (unsigned short)v;
    }
}

// ---------------- Kernel B: interpolate ----------------
__global__ __launch_bounds__(1024) void interp(
        const f32x4* __restrict__ xs4, const float* __restrict__ xp,
        const float* __restrict__ recg, const unsigned short* __restrict__ tbl,
        f32x4* __restrict__ out4, int n4, int nk) {
    __shared__ __align__(16) float srec[NREC * 2];   // 131104 B
    __shared__ unsigned short sT[NB];                // 32512 B  (total 163616 <= 160 KiB)

    {   // fills: float->float and u16->u16 only (TBAA-safe)
        const f32x4* rg4 = (const f32x4*)recg;
        f32x4* sr4 = (f32x4*)srec;
        int n = (NREC * 2) / 4;                      // 8194
        for (int i = threadIdx.x; i < n; i += 1024) sr4[i] = rg4[i];
        for (int i = threadIdx.x; i < NB; i += 1024) sT[i] = tbl[i];
    }

    float lo = xp[0];
    float inv_w = (float)NB / (xp[nk - 1] - lo);
    __syncthreads();

    const f32x2* sr2 = (const f32x2*)srec;           // record view (float-typed)

    int tid = blockIdx.x * blockDim.x + threadIdx.x;
    int T = gridDim.x * blockDim.x;

    int t = tid;
    f32x4 xa, xb;
    bool has1 = (t < n4), has2 = (t + T < n4);
    if (has1) xa = __builtin_nontemporal_load(&xs4[t]);
    if (has2) xb = __builtin_nontemporal_load(&xs4[t + T]);

    while (has1) {
        int tn = t + 2 * T;
        f32x4 xan, xbn;
        bool h1n = (tn < n4), h2n = (tn + T < n4);
        if (h1n) xan = __builtin_nontemporal_load(&xs4[tn]);          // prefetch
        if (h2n) xbn = __builtin_nontemporal_load(&xs4[tn + T]);

        f32x4 res[2];
        #pragma unroll
        for (int half = 0; half < 2; half++) {
            f32x4 xq = (half == 0) ? xa : xb;
            float x[4] = {xq.x, xq.y, xq.z, xq.w};
            int base[4];
            f32x2 r0[4], r1[4], r2[4], r3[4];
            #pragma unroll
            for (int k = 0; k < 4; k++) {
                int b = bucket_of(x[k], lo, inv_w);   // >= 0 since x >= xp[0]
                b = min(b, NB - 1);
                base[k] = (int)sT[b];
                r0[k] = sr2[base[k]];                 // adjacent pairs ->
                r1[k] = sr2[base[k] + 1];             //   2x ds_read2_b64
                r2[k] = sr2[base[k] + 2];
                r3[k] = sr2[base[k] + 3];
            }
            #pragma unroll
            for (int k = 0; k < 4; k++) {
                float xk = x[k];
                float xi = r0[k].x, ys = r0[k].y;     // x_base <= xk guaranteed
                if (r1[k].x <= xk) { xi = r1[k].x; ys = r1[k].y; }
                if (r2[k].x <= xk) { xi = r2[k].x; ys = r2[k].y; }
                bool tail = (r3[k].x <= xk);
                if (tail) {
                    // window exhausted (P ~ 2%): linear walk, exec-masked
                    int j = base[k] + 3;
                    while (srec[2 * (j + 1)] <= xk) j++;
                    xi = srec[2 * j]; ys = srec[2 * j + 1];
                }
                res[half][k] = lerp_ys(xk - xi, ys);
            }
        }
        __builtin_nontemporal_store(res[0], &out4[t]);
        if (has2) __builtin_nontemporal_store(res[1], &out4[t + T]);

        t = tn; xa = xan; xb = xbn; has1 = h1n; has2 = h2n;
    }
}

extern "C" void kernel_launch(void* const* d_in, const int* in_sizes, int n_in,
                              void* d_out, int out_size, void* d_ws, size_t ws_size,
                              hipStream_t stream) {
    const float* xs = (const float*)d_in[0];
    const float* xp = (const float*)d_in[1];
    const float* yp = (const float*)d_in[2];
    int ns = in_sizes[0];
    int nk = in_sizes[1];

    // Workspace: recg (NREC*2 f32) | tbl (NB u16)
    float* recg = (float*)d_ws;
    unsigned short* tbl = (unsigned short*)((char*)d_ws + (size_t)NREC * 2 * sizeof(float));

    int na = (nk + PADR > NB ? nk + PADR : NB);
    build_tbl<<<(na + 255) / 256, 256, 0, stream>>>(xp, yp, recg, tbl, nk);

    int n4 = ns / 4;
    interp<<<256, 1024, 0, stream>>>((const f32x4*)xs, xp, recg, tbl,
                                     (f32x4*)d_out, n4, nk);
}

// Round 9
// 103.765 us; speedup vs baseline: 1.0299x; 1.0163x over previous
//
#include <hip/hip_runtime.h>

// Linear interpolation: 8.4M samples vs 16384 sorted knots.
// R9: R8's LDS layout (interleaved 8B records {f32 x, packed f16 y,s} +
// u16 bucket->lo table, NB=16256) with a restructured streaming pipeline:
// 8 stages x 1 quad, software-pipelined depth 3 (3 quads in flight/thread,
// evenly issued) to cover ~900-cyc nontemporal HBM load latency with only
// 16 waves/CU. Inner window/select logic identical to R8 (proven correct).

#define NB 16256            // u16 table = 32512 B LDS
#define NKMAX 16384
#define PADR 4              // +INF pad records
#define NREC (NKMAX + PADR)

typedef float f32x4 __attribute__((ext_vector_type(4)));
typedef float f32x2 __attribute__((ext_vector_type(2)));

__device__ __forceinline__ int bucket_of(float v, float lo, float inv_w) {
    // MUST be the identical expression in both kernels (monotone in fp32).
    return (int)((v - lo) * inv_w);
}

__device__ __forceinline__ float pack_ys_f(float y, float s) {
    _Float16 hy = (_Float16)y, hs = (_Float16)s;
    unsigned short uy = __builtin_bit_cast(unsigned short, hy);
    unsigned short us = __builtin_bit_cast(unsigned short, hs);
    unsigned u = (unsigned)uy | ((unsigned)us << 16);
    return __builtin_bit_cast(float, u);
}

__device__ __forceinline__ float lerp_ys(float dx, float ysf) {
    unsigned u = __builtin_bit_cast(unsigned, ysf);
    float hy = (float)__builtin_bit_cast(_Float16, (unsigned short)(u & 0xffffu));
    float hs = (float)__builtin_bit_cast(_Float16, (unsigned short)(u >> 16));
    return fmaf(dx, hs, hy);
}

// ---------------- Kernel A: interleaved records + bucket->lo table ----------------
__global__ void build_tbl(const float* __restrict__ xp, const float* __restrict__ yp,
                          float* __restrict__ recg, unsigned short* __restrict__ tbl,
                          int nk) {
    int i = blockIdx.x * blockDim.x + threadIdx.x;
    float lo = xp[0];
    float inv_w = (float)NB / (xp[nk - 1] - lo);
    if (i < nk + PADR) {
        float x, y, s;
        if (i < nk) {
            x = xp[i]; y = yp[i];
            s = (i < nk - 1) ? (yp[i + 1] - y) / (xp[i + 1] - x) : 0.0f;
        } else {                      // pad: +INF knot, never selected
            x = __builtin_inff(); y = 0.0f; s = 0.0f;
        }
        recg[2 * i]     = x;
        recg[2 * i + 1] = pack_ys_f(y, s);
    }
    if (i < NB) {
        // lo(i) = largest j with bucket(xp[j]) <= i-1   (monotone predicate)
        int v = 0;
        if (i > 0) {
            int loj = -1, hij = nk - 1;
            while (loj < hij) {
                int mid = (loj + hij + 1) >> 1;
                if (bucket_of(xp[mid], lo, inv_w) <= i - 1) loj = mid; else hij = mid - 1;
            }
            v = loj < 0 ? 0 : (loj > nk - 2 ? nk - 2 : loj);
        }
        tbl[i] = (unsigned short)v;
    }
}

// ---------------- Kernel B: interpolate ----------------
__global__ __launch_bounds__(1024) void interp(
        const f32x4* __restrict__ xs4, const float* __restrict__ xp,
        const float* __restrict__ recg, const unsigned short* __restrict__ tbl,
        f32x4* __restrict__ out4, int n4, int nk) {
    __shared__ __align__(16) float srec[NREC * 2];   // 131104 B
    __shared__ unsigned short sT[NB];                // 32512 B

    {   // fills: float->float and u16->u16 only (TBAA-safe)
        const f32x4* rg4 = (const f32x4*)recg;
        f32x4* sr4 = (f32x4*)srec;
        int n = (NREC * 2) / 4;
        for (int i = threadIdx.x; i < n; i += 1024) sr4[i] = rg4[i];
        for (int i = threadIdx.x; i < NB; i += 1024) sT[i] = tbl[i];
    }

    float lo = xp[0];
    float inv_w = (float)NB / (xp[nk - 1] - lo);
    __syncthreads();

    const f32x2* sr2 = (const f32x2*)srec;

    int tid = blockIdx.x * blockDim.x + threadIdx.x;
    int T = gridDim.x * blockDim.x;

    // Per-quad processing (R8-proven window/select logic).
    auto process = [&](f32x4 xq) -> f32x4 {
        float x[4] = {xq.x, xq.y, xq.z, xq.w};
        int base[4];
        f32x2 r0[4], r1[4], r2[4], r3[4];
        #pragma unroll
        for (int k = 0; k < 4; k++) {
            int b = bucket_of(x[k], lo, inv_w);   // >= 0 since x >= xp[0]
            b = min(b, NB - 1);
            base[k] = (int)sT[b];
            r0[k] = sr2[base[k]];                 // adjacent pairs ->
            r1[k] = sr2[base[k] + 1];             //   2x ds_read2_b64
            r2[k] = sr2[base[k] + 2];
            r3[k] = sr2[base[k] + 3];
        }
        f32x4 res;
        #pragma unroll
        for (int k = 0; k < 4; k++) {
            float xk = x[k];
            float xi = r0[k].x, ys = r0[k].y;     // x_base <= xk guaranteed
            if (r1[k].x <= xk) { xi = r1[k].x; ys = r1[k].y; }
            if (r2[k].x <= xk) { xi = r2[k].x; ys = r2[k].y; }
            bool tail = (r3[k].x <= xk);
            if (tail) {
                // window exhausted (P ~ 2%): linear walk, exec-masked
                int j = base[k] + 3;
                while (srec[2 * (j + 1)] <= xk) j++;
                xi = srec[2 * j]; ys = srec[2 * j + 1];
            }
            res[k] = lerp_ys(xk - xi, ys);
        }
        return res;
    };

    if (n4 == 8 * T) {
        // Exact shape: 8 stages/thread, depth-3 software pipeline, fully
        // unrolled -> 3 streaming quads always in flight, evenly issued.
        f32x4 buf[8];
        #pragma unroll
        for (int s = 0; s < 3; s++)
            buf[s] = __builtin_nontemporal_load(&xs4[tid + s * T]);
        #pragma unroll
        for (int s = 0; s < 8; s++) {
            if (s + 3 < 8)
                buf[s + 3] = __builtin_nontemporal_load(&xs4[tid + (s + 3) * T]);
            f32x4 res = process(buf[s]);
            __builtin_nontemporal_store(res, &out4[tid + s * T]);
        }
    } else {
        // Generic fallback (any shape).
        for (int t = tid; t < n4; t += T) {
            f32x4 xq = __builtin_nontemporal_load(&xs4[t]);
            f32x4 res = process(xq);
            __builtin_nontemporal_store(res, &out4[t]);
        }
    }
}

extern "C" void kernel_launch(void* const* d_in, const int* in_sizes, int n_in,
                              void* d_out, int out_size, void* d_ws, size_t ws_size,
                              hipStream_t stream) {
    const float* xs = (const float*)d_in[0];
    const float* xp = (const float*)d_in[1];
    const float* yp = (const float*)d_in[2];
    int ns = in_sizes[0];
    int nk = in_sizes[1];

    // Workspace: recg (NREC*2 f32) | tbl (NB u16)
    float* recg = (float*)d_ws;
    unsigned short* tbl = (unsigned short*)((char*)d_ws + (size_t)NREC * 2 * sizeof(float));

    int na = (nk + PADR > NB ? nk + PADR : NB);
    build_tbl<<<(na + 255) / 256, 256, 0, stream>>>(xp, yp, recg, tbl, nk);

    int n4 = ns / 4;
    interp<<<256, 1024, 0, stream>>>((const f32x4*)xs, xp, recg, tbl,
                                     (f32x4*)d_out, n4, nk);
}